// Round 1
// baseline (1145.092 us; speedup 1.0000x reference)
//
#include <hip/hip_runtime.h>
#include <math.h>

#define B_  8
#define L_  4096
#define C1  128
#define DI  256
#define NC  32
#define LC  128

__device__ __forceinline__ float fsilu(float x){ return x / (1.f + __expf(-x)); }

// ---------------- K1: proj_in + silu.  x (b,64,L) -> t1 channel-major (b,128,L)
__global__ __launch_bounds__(256) void k_proj_in(const float* __restrict__ x,
      const float* __restrict__ w, const float* __restrict__ bias,
      float* __restrict__ t1){
  __shared__ float Xs[64*64];
  int blk = blockIdx.x;
  int b = blk >> 6;            // 64 tiles of 64 tokens
  int l0 = (blk & 63) << 6;
  int tid = threadIdx.x;
  for (int idx = tid; idx < 64*64; idx += 256){
    int k = idx >> 6, ti = idx & 63;
    Xs[idx] = x[(b*64 + k)*L_ + l0 + ti];
  }
  __syncthreads();
  for (int s = 0; s < 32; ++s){
    int oi = tid + s*256;
    int j = oi >> 6, ti = oi & 63;   // j wave-uniform -> w via s_load
    float acc = bias[j];
    #pragma unroll 8
    for (int k = 0; k < 64; ++k) acc += Xs[k*64+ti]*w[j*64+k];
    t1[(b*128 + j)*L_ + l0 + ti] = fsilu(acc);
  }
}

// ---------------- K2: in_proj. t1 (b,128,L) -> xz channel-major (b,512,L)
__global__ __launch_bounds__(256) void k_in_proj(const float* __restrict__ t1,
      const float* __restrict__ w, float* __restrict__ xz){
  __shared__ float As[16*132];
  int blk = blockIdx.x;
  int b = blk >> 8;            // 256 tiles of 16 tokens
  int l0 = (blk & 255) << 4;
  int tid = threadIdx.x;
  for (int idx = tid; idx < 16*128; idx += 256){
    int k = idx >> 4, ti = idx & 15;
    As[ti*132 + k] = t1[(b*128+k)*L_ + l0 + ti];
  }
  __syncthreads();
  float acc0[16], acc1[16];
  #pragma unroll
  for (int ti=0; ti<16; ++ti){ acc0[ti]=0.f; acc1[ti]=0.f; }
  int j0 = tid, j1 = tid + 256;
  for (int k0 = 0; k0 < 128; k0 += 4){
    float4 w0 = *(const float4*)&w[j0*128 + k0];
    float4 w1 = *(const float4*)&w[j1*128 + k0];
    #pragma unroll
    for (int ti=0; ti<16; ++ti){
      float4 a = *(const float4*)&As[ti*132 + k0];
      acc0[ti] += a.x*w0.x + a.y*w0.y + a.z*w0.z + a.w*w0.w;
      acc1[ti] += a.x*w1.x + a.y*w1.y + a.z*w1.z + a.w*w1.w;
    }
  }
  #pragma unroll
  for (int ti=0; ti<16; ++ti){
    xz[(b*512 + j0)*L_ + l0 + ti] = acc0[ti];
    xz[(b*512 + j1)*L_ + l0 + ti] = acc1[ti];
  }
}

// ---------------- K3: causal depthwise conv1d + silu. xm half of xz -> u (b,256,L)
__global__ __launch_bounds__(256) void k_conv1d(const float* __restrict__ xz,
      const float* __restrict__ w, const float* __restrict__ bias,
      float* __restrict__ u){
  int id = blockIdx.x*256 + threadIdx.x;   // (b*256+d)*L + l
  int l = id & (L_-1);
  int bd = id >> 12;
  int d = bd & 255;
  int b = bd >> 8;
  const float* src = xz + (b*512 + d)*L_;
  float acc = bias[d];
  #pragma unroll
  for (int k = 0; k < 4; ++k){
    int ll = l + k - 3;
    float v = (ll >= 0) ? src[ll] : 0.f;
    acc += w[d*4+k]*v;
  }
  u[id] = fsilu(acc);
}

// ---------------- K4: x_proj. u (b,256,L) -> dbl token-major (b*L, 136)
__global__ __launch_bounds__(256) void k_x_proj(const float* __restrict__ u,
      const float* __restrict__ w, float* __restrict__ dbl){
  __shared__ float As[32*260];
  int blk = blockIdx.x;
  int b = blk >> 7;            // 128 tiles of 32 tokens
  int l0 = (blk & 127) << 5;
  int tid = threadIdx.x;
  for (int idx = tid; idx < 32*256; idx += 256){
    int k = idx >> 5, ti = idx & 31;
    As[ti*260 + k] = u[(b*256+k)*L_ + l0 + ti];
  }
  __syncthreads();
  if (tid < 136){
    float acc[32];
    #pragma unroll
    for (int ti=0; ti<32; ++ti) acc[ti]=0.f;
    for (int k0=0; k0<256; k0+=4){
      float4 w4 = *(const float4*)&w[tid*256+k0];
      #pragma unroll
      for (int ti=0; ti<32; ++ti){
        float4 a = *(const float4*)&As[ti*260+k0];
        acc[ti] += a.x*w4.x + a.y*w4.y + a.z*w4.z + a.w*w4.w;
      }
    }
    for (int ti=0; ti<32; ++ti)
      dbl[(size_t)(b*L_ + l0 + ti)*136 + tid] = acc[ti];
  }
}

// ---------------- K5: dt_proj + softplus. dbl[:, :8] -> dt (b,256,L)
__global__ __launch_bounds__(256) void k_dt_proj(const float* __restrict__ dbl,
      const float* __restrict__ w, const float* __restrict__ bias,
      float* __restrict__ dt){
  int id = blockIdx.x*256 + threadIdx.x;
  int l = id & (L_-1);
  int bd = id >> 12;
  int d = bd & 255;
  int b = bd >> 8;
  const float* row = dbl + (size_t)(b*L_ + l)*136;
  float acc = bias[d];
  #pragma unroll
  for (int r=0;r<8;++r) acc += row[r]*w[d*8+r];
  float sp = (acc > 15.f) ? acc : logf(1.f + __expf(acc));
  dt[id] = sp;
}

// ---------------- K6: scan phase 1 — per-chunk local scan: P (decay product), S (end state)
// wave handles 4 chains (b,d0..d0+3,c); lane = di*16+nq, 4 states (n=4nq..4nq+3) per lane
__global__ __launch_bounds__(256) void k_scan1(const float* __restrict__ dt,
      const float* __restrict__ u, const float* __restrict__ dbl,
      const float* __restrict__ A_log,
      float* __restrict__ P, float* __restrict__ S){
  int wg = blockIdx.x*4 + (threadIdx.x >> 6);
  int lane = threadIdx.x & 63;
  int di = lane >> 4, nq = lane & 15;
  int c  = wg & (NC-1);
  int dq = (wg >> 5) & 63;
  int b  = wg >> 11;
  int d  = dq*4 + di;
  int n0 = nq*4;
  float4 al = *(const float4*)&A_log[d*64 + n0];
  float A0=-__expf(al.x), A1=-__expf(al.y), A2=-__expf(al.z), A3=-__expf(al.w);
  float h0=0,h1=0,h2=0,h3=0, p0=1,p1=1,p2=1,p3=1;
  const float* dtp = dt + (b*256+d)*L_ + c*LC;
  const float* up  = u  + (b*256+d)*L_ + c*LC;
  const float* dbase = dbl + (size_t)(b*L_ + c*LC)*136;
  for (int i=0;i<LC;++i){
    float dtv = dtp[i];
    float uv  = up[i];
    float4 Bv = *(const float4*)&dbase[(size_t)i*136 + 8 + n0];
    float du = dtv*uv;
    float e0=__expf(dtv*A0), e1=__expf(dtv*A1), e2=__expf(dtv*A2), e3=__expf(dtv*A3);
    h0 = h0*e0 + du*Bv.x; h1 = h1*e1 + du*Bv.y;
    h2 = h2*e2 + du*Bv.z; h3 = h3*e3 + du*Bv.w;
    p0*=e0; p1*=e1; p2*=e2; p3*=e3;
  }
  size_t idx = ((size_t)((b*256+d)*NC + c))*64 + n0;
  *(float4*)&S[idx] = make_float4(h0,h1,h2,h3);
  *(float4*)&P[idx] = make_float4(p0,p1,p2,p3);
}

// ---------------- K7: scan phase 2 — cross-chunk scan; writes chunk-START state into P
__global__ __launch_bounds__(256) void k_scan2(float* __restrict__ P, const float* __restrict__ S){
  int g = blockIdx.x*256 + threadIdx.x;  // (b*256+d)*64 + n
  int n = g & 63;
  int bd = g >> 6;
  float H = 0.f;
  size_t base = ((size_t)bd*NC)*64 + n;
  for (int c=0;c<NC;++c){
    size_t idx = base + (size_t)c*64;
    float p = P[idx], s = S[idx];
    P[idx] = H;                 // chunk-start state for phase 3
    H = H*p + s;
  }
}

// ---------------- K8: scan phase 3 — replay with correct h0, emit y; fused +u*D, *silu(z); in-place over dt
__global__ __launch_bounds__(256) void k_scan3(float* __restrict__ dt,
      const float* __restrict__ u, const float* __restrict__ dbl,
      const float* __restrict__ xz, const float* __restrict__ A_log,
      const float* __restrict__ P, const float* __restrict__ Dp){
  int wg = blockIdx.x*4 + (threadIdx.x >> 6);
  int lane = threadIdx.x & 63;
  int di = lane >> 4, nq = lane & 15;
  int c  = wg & (NC-1);
  int dq = (wg >> 5) & 63;
  int b  = wg >> 11;
  int d  = dq*4 + di;
  int n0 = nq*4;
  float4 al = *(const float4*)&A_log[d*64 + n0];
  float A0=-__expf(al.x), A1=-__expf(al.y), A2=-__expf(al.z), A3=-__expf(al.w);
  size_t sidx = ((size_t)((b*256+d)*NC + c))*64 + n0;
  float4 hv = *(const float4*)&P[sidx];
  float h0=hv.x,h1=hv.y,h2=hv.z,h3=hv.w;
  float Dd = Dp[d];
  float* dtp = dt + (b*256+d)*L_ + c*LC;
  const float* up  = u  + (b*256+d)*L_ + c*LC;
  const float* zp  = xz + (size_t)(b*512 + 256 + d)*L_ + c*LC;
  const float* dbase = dbl + (size_t)(b*L_ + c*LC)*136;
  for (int i=0;i<LC;++i){
    float dtv = dtp[i];
    float uv  = up[i];
    const float* rw = &dbase[(size_t)i*136];
    float4 Bv = *(const float4*)&rw[8 + n0];
    float4 Cv = *(const float4*)&rw[72 + n0];
    float du = dtv*uv;
    float e0=__expf(dtv*A0), e1=__expf(dtv*A1), e2=__expf(dtv*A2), e3=__expf(dtv*A3);
    h0 = h0*e0 + du*Bv.x; h1 = h1*e1 + du*Bv.y;
    h2 = h2*e2 + du*Bv.z; h3 = h3*e3 + du*Bv.w;
    float part = h0*Cv.x + h1*Cv.y + h2*Cv.z + h3*Cv.w;
    part += __shfl_xor(part, 1);
    part += __shfl_xor(part, 2);
    part += __shfl_xor(part, 4);
    part += __shfl_xor(part, 8);   // sum over the 16-lane (64-state) group
    if (nq == 0){
      float zv = zp[i];
      dtp[i] = (part + uv*Dd) * fsilu(zv);   // y, written over dt (read-before-write same iter)
    }
  }
}

// ---------------- K9: out_proj. y=dt (b,256,L) -> t2 token-major (b*L,128)
__global__ __launch_bounds__(256) void k_out_proj(const float* __restrict__ y,
      const float* __restrict__ w, float* __restrict__ t2){
  __shared__ float As[16*260];
  int blk = blockIdx.x;
  int b = blk >> 8;
  int l0 = (blk & 255) << 4;
  int tid = threadIdx.x;
  for (int idx = tid; idx < 16*256; idx += 256){
    int k = idx >> 4, ti = idx & 15;
    As[ti*260 + k] = y[(b*256+k)*L_ + l0 + ti];
  }
  __syncthreads();
  int j = tid & 127;
  int ti0 = (tid >> 7) * 8;
  float acc[8];
  #pragma unroll
  for (int t=0;t<8;++t) acc[t]=0.f;
  for (int k0=0;k0<256;k0+=4){
    float4 w4 = *(const float4*)&w[j*256+k0];
    #pragma unroll
    for (int t=0;t<8;++t){
      float4 a = *(const float4*)&As[(ti0+t)*260+k0];
      acc[t] += a.x*w4.x + a.y*w4.y + a.z*w4.z + a.w*w4.w;
    }
  }
  #pragma unroll
  for (int t=0;t<8;++t)
    t2[(size_t)(b*L_ + l0 + ti0 + t)*128 + j] = acc[t];
}

// ---------------- K10: proj_out + bias + LayerNorm -> t3 channel-major (b,128,L)
__global__ __launch_bounds__(128) void k_proj_out_ln(const float* __restrict__ t2,
      const float* __restrict__ w, const float* __restrict__ bias,
      const float* __restrict__ g, const float* __restrict__ bb,
      float* __restrict__ t3){
  __shared__ float As[16*132];
  __shared__ float Ps[16*8], Qs[16*8];
  __shared__ float Mu[16], Rs[16];
  int blk = blockIdx.x;
  int b = blk >> 8;
  int l0 = (blk & 255) << 4;
  int tid = threadIdx.x;
  for (int idx = tid; idx < 16*128; idx += 128){
    int ti = idx >> 7, k = idx & 127;
    As[ti*132 + k] = t2[(size_t)(b*L_ + l0 + ti)*128 + k];
  }
  __syncthreads();
  int j = tid;
  float acc[16];
  #pragma unroll
  for (int t=0;t<16;++t) acc[t]=bias[j];
  for (int k0=0;k0<128;k0+=4){
    float4 w4 = *(const float4*)&w[j*128+k0];
    #pragma unroll
    for (int t=0;t<16;++t){
      float4 a = *(const float4*)&As[t*132+k0];
      acc[t] += a.x*w4.x + a.y*w4.y + a.z*w4.z + a.w*w4.w;
    }
  }
  __syncthreads();                 // done reading As
  #pragma unroll
  for (int t=0;t<16;++t) As[t*132 + j] = acc[t];
  __syncthreads();
  {
    int ti = tid >> 3, s = tid & 7;
    float sm=0.f, sq=0.f;
    for (int q=0;q<16;++q){
      float v = As[ti*132 + s*16 + q];
      sm += v; sq += v*v;
    }
    Ps[ti*8+s]=sm; Qs[ti*8+s]=sq;
  }
  __syncthreads();
  if (tid < 16){
    float sm=0.f,sq=0.f;
    for (int q=0;q<8;++q){ sm+=Ps[tid*8+q]; sq+=Qs[tid*8+q]; }
    float mu = sm*(1.f/128.f);
    float var = sq*(1.f/128.f) - mu*mu;
    Mu[tid]=mu; Rs[tid]=rsqrtf(var + 1e-5f);
  }
  __syncthreads();
  float gj = g[j], bj = bb[j];
  #pragma unroll
  for (int t=0;t<16;++t){
    float v = (As[t*132+j]-Mu[t])*Rs[t]*gj + bj;
    t3[(size_t)(b*128+j)*L_ + l0 + t] = v;
  }
}

// ---------------- K11: instance norm over L per (b,c) + leaky relu -> f (b,128,L)
__global__ __launch_bounds__(256) void k_inorm(const float* __restrict__ t3,
      const float* __restrict__ g, const float* __restrict__ bb,
      float* __restrict__ f){
  __shared__ float Sm[4], Sq[4];
  __shared__ float MuS, RsS;
  int bc = blockIdx.x;
  int c = bc & 127;
  const float* src = t3 + (size_t)bc*L_;
  int tid = threadIdx.x;
  float sm=0.f, sq=0.f;
  for (int i=tid;i<L_;i+=256){ float v=src[i]; sm+=v; sq+=v*v; }
  #pragma unroll
  for (int off=32;off;off>>=1){ sm += __shfl_xor(sm,off); sq += __shfl_xor(sq,off); }
  if ((tid & 63)==0){ Sm[tid>>6]=sm; Sq[tid>>6]=sq; }
  __syncthreads();
  if (tid==0){
    float a=Sm[0]+Sm[1]+Sm[2]+Sm[3], q=Sq[0]+Sq[1]+Sq[2]+Sq[3];
    float mu=a*(1.f/L_), var=q*(1.f/L_)-mu*mu;
    MuS=mu; RsS=rsqrtf(var+1e-5f);
  }
  __syncthreads();
  float mu=MuS, rs=RsS, gc=g[c], b2=bb[c];
  float* dst = f + (size_t)bc*L_;
  for (int i=tid;i<L_;i+=256){
    float v=(src[i]-mu)*rs*gc + b2;
    dst[i] = (v>=0.f)? v : 0.01f*v;
  }
}

// ---------------- K12: 3x3 SAME conv, 128->128. f (b,128,64,64) -> out
__global__ __launch_bounds__(256) void k_conv2d(const float* __restrict__ f,
      const float* __restrict__ w, const float* __restrict__ bias,
      float* __restrict__ out){
  __shared__ float Fs[18*20];
  int blk = blockIdx.x;
  int tile = blk & 15;
  int cog = (blk >> 4) & 15;
  int b = blk >> 8;
  int h0 = (tile >> 2) * 16, w0 = (tile & 3) * 16;
  int co0 = cog*8;
  int tid = threadIdx.x;
  int tx = tid & 15, ty = tid >> 4;
  float acc[8];
  #pragma unroll
  for (int i=0;i<8;++i) acc[i]=0.f;
  for (int ci=0; ci<128; ++ci){
    __syncthreads();
    for (int idx=tid; idx<18*18; idx+=256){
      int r = idx/18, cc = idx%18;
      int h = h0-1+r, ww = w0-1+cc;
      float v = 0.f;
      if (h>=0 && h<64 && ww>=0 && ww<64)
        v = f[((size_t)(b*128+ci))*4096 + h*64 + ww];
      Fs[r*20+cc] = v;
    }
    __syncthreads();
    const float* wp = w + ((size_t)co0*128 + ci)*9;    // wave-uniform -> s_load
    #pragma unroll
    for (int ky=0;ky<3;++ky)
    #pragma unroll
    for (int kx=0;kx<3;++kx){
      float lv = Fs[(ty+ky)*20 + tx+kx];
      #pragma unroll
      for (int co=0;co<8;++co)
        acc[co] += lv * wp[(size_t)co*128*9 + ky*3+kx];
    }
  }
  #pragma unroll
  for (int co=0;co<8;++co)
    out[((size_t)(b*128+co0+co))*4096 + (h0+ty)*64 + (w0+tx)] = acc[co] + bias[co0+co];
}

extern "C" void kernel_launch(void* const* d_in, const int* in_sizes, int n_in,
                              void* d_out, int out_size, void* d_ws, size_t ws_size,
                              hipStream_t stream){
  const float* x     = (const float*)d_in[0];
  const float* piw   = (const float*)d_in[1];
  const float* pib   = (const float*)d_in[2];
  const float* ipw   = (const float*)d_in[3];
  const float* c1w   = (const float*)d_in[4];
  const float* c1b   = (const float*)d_in[5];
  const float* xpw   = (const float*)d_in[6];
  const float* dtw   = (const float*)d_in[7];
  const float* dtb   = (const float*)d_in[8];
  const float* alog  = (const float*)d_in[9];
  const float* Dp    = (const float*)d_in[10];
  const float* opw   = (const float*)d_in[11];
  const float* pow_  = (const float*)d_in[12];
  const float* pob   = (const float*)d_in[13];
  const float* lng   = (const float*)d_in[14];
  const float* lnb   = (const float*)d_in[15];
  const float* ing   = (const float*)d_in[16];
  const float* inb   = (const float*)d_in[17];
  const float* c2w   = (const float*)d_in[18];
  const float* c2b   = (const float*)d_in[19];
  float* out = (float*)d_out;

  // workspace layout (floats); total 46,399,488 floats = 185.6 MB
  float* ws  = (float*)d_ws;
  float* t1  = ws;                    // 4,194,304   (b,128,L); reused as t2 (token-major) after scan
  float* xz  = t1 + 4194304;          // 16,777,216  (b,512,L)
  float* u   = xz + 16777216;         // 8,388,608   (b,256,L); reused as f after instnorm
  float* dbl = u  + 8388608;          // 4,456,448   (b*L,136); reused as t3 (b,128,L) after scan
  float* dt  = dbl + 4456448;         // 8,388,608   (b,256,L); y written in place by scan3
  float* S   = dt + 8388608;          // 4,194,304
  float* P   = t1;                    // alias t1 (free between in_proj and out_proj)
  float* t2  = t1;
  float* t3  = dbl;
  float* fbuf= u;

  k_proj_in   <<<dim3(512),   dim3(256), 0, stream>>>(x, piw, pib, t1);
  k_in_proj   <<<dim3(2048),  dim3(256), 0, stream>>>(t1, ipw, xz);
  k_conv1d    <<<dim3(32768), dim3(256), 0, stream>>>(xz, c1w, c1b, u);
  k_x_proj    <<<dim3(1024),  dim3(256), 0, stream>>>(u, xpw, dbl);
  k_dt_proj   <<<dim3(32768), dim3(256), 0, stream>>>(dbl, dtw, dtb, dt);
  k_scan1     <<<dim3(4096),  dim3(256), 0, stream>>>(dt, u, dbl, alog, P, S);
  k_scan2     <<<dim3(512),   dim3(256), 0, stream>>>(P, S);
  k_scan3     <<<dim3(4096),  dim3(256), 0, stream>>>(dt, u, dbl, xz, alog, P, Dp);
  k_out_proj  <<<dim3(2048),  dim3(256), 0, stream>>>(dt, opw, t2);
  k_proj_out_ln<<<dim3(2048), dim3(128), 0, stream>>>(t2, pow_, pob, lng, lnb, t3);
  k_inorm     <<<dim3(1024),  dim3(256), 0, stream>>>(t3, ing, inb, fbuf);
  k_conv2d    <<<dim3(2048),  dim3(256), 0, stream>>>(fbuf, c2w, c2b, out);
}

// Round 2
// 1140.508 us; speedup vs baseline: 1.0040x; 1.0040x over previous
//
#include <hip/hip_runtime.h>
#include <math.h>

#define B_  8
#define L_  4096
#define C1  128
#define DI  256
#define NC  32
#define LC  128

__device__ __forceinline__ float fsilu(float x){ return x / (1.f + __expf(-x)); }

// ---------------- K1: proj_in + silu.  x (b,64,L) -> t1 channel-major (b,128,L)
__global__ __launch_bounds__(256) void k_proj_in(const float* __restrict__ x,
      const float* __restrict__ w, const float* __restrict__ bias,
      float* __restrict__ t1){
  __shared__ float Xs[64*64];
  int blk = blockIdx.x;
  int b = blk >> 6;            // 64 tiles of 64 tokens
  int l0 = (blk & 63) << 6;
  int tid = threadIdx.x;
  for (int idx = tid; idx < 64*64; idx += 256){
    int k = idx >> 6, ti = idx & 63;
    Xs[idx] = x[(b*64 + k)*L_ + l0 + ti];
  }
  __syncthreads();
  for (int s = 0; s < 32; ++s){
    int oi = tid + s*256;
    int j = oi >> 6, ti = oi & 63;   // j wave-uniform -> w via s_load
    float acc = bias[j];
    #pragma unroll 8
    for (int k = 0; k < 64; ++k) acc += Xs[k*64+ti]*w[j*64+k];
    t1[(b*128 + j)*L_ + l0 + ti] = fsilu(acc);
  }
}

// ---------------- K2: in_proj. t1 (b,128,L) -> xz channel-major (b,512,L)
__global__ __launch_bounds__(256) void k_in_proj(const float* __restrict__ t1,
      const float* __restrict__ w, float* __restrict__ xz){
  __shared__ float As[16*132];
  int blk = blockIdx.x;
  int b = blk >> 8;            // 256 tiles of 16 tokens
  int l0 = (blk & 255) << 4;
  int tid = threadIdx.x;
  for (int idx = tid; idx < 16*128; idx += 256){
    int k = idx >> 4, ti = idx & 15;
    As[ti*132 + k] = t1[(b*128+k)*L_ + l0 + ti];
  }
  __syncthreads();
  float acc0[16], acc1[16];
  #pragma unroll
  for (int ti=0; ti<16; ++ti){ acc0[ti]=0.f; acc1[ti]=0.f; }
  int j0 = tid, j1 = tid + 256;
  for (int k0 = 0; k0 < 128; k0 += 4){
    float4 w0 = *(const float4*)&w[j0*128 + k0];
    float4 w1 = *(const float4*)&w[j1*128 + k0];
    #pragma unroll
    for (int ti=0; ti<16; ++ti){
      float4 a = *(const float4*)&As[ti*132 + k0];
      acc0[ti] += a.x*w0.x + a.y*w0.y + a.z*w0.z + a.w*w0.w;
      acc1[ti] += a.x*w1.x + a.y*w1.y + a.z*w1.z + a.w*w1.w;
    }
  }
  #pragma unroll
  for (int ti=0; ti<16; ++ti){
    xz[(b*512 + j0)*L_ + l0 + ti] = acc0[ti];
    xz[(b*512 + j1)*L_ + l0 + ti] = acc1[ti];
  }
}

// ---------------- K3: causal depthwise conv1d + silu. xm half of xz -> u (b,256,L)
__global__ __launch_bounds__(256) void k_conv1d(const float* __restrict__ xz,
      const float* __restrict__ w, const float* __restrict__ bias,
      float* __restrict__ u){
  int id = blockIdx.x*256 + threadIdx.x;   // (b*256+d)*L + l
  int l = id & (L_-1);
  int bd = id >> 12;
  int d = bd & 255;
  int b = bd >> 8;
  const float* src = xz + (b*512 + d)*L_;
  float acc = bias[d];
  #pragma unroll
  for (int k = 0; k < 4; ++k){
    int ll = l + k - 3;
    float v = (ll >= 0) ? src[ll] : 0.f;
    acc += w[d*4+k]*v;
  }
  u[id] = fsilu(acc);
}

// ---------------- K4: x_proj. u (b,256,L) -> dbl token-major (b*L, 136)
__global__ __launch_bounds__(256) void k_x_proj(const float* __restrict__ u,
      const float* __restrict__ w, float* __restrict__ dbl){
  __shared__ float As[32*260];
  int blk = blockIdx.x;
  int b = blk >> 7;            // 128 tiles of 32 tokens
  int l0 = (blk & 127) << 5;
  int tid = threadIdx.x;
  for (int idx = tid; idx < 32*256; idx += 256){
    int k = idx >> 5, ti = idx & 31;
    As[ti*260 + k] = u[(b*256+k)*L_ + l0 + ti];
  }
  __syncthreads();
  if (tid < 136){
    float acc[32];
    #pragma unroll
    for (int ti=0; ti<32; ++ti) acc[ti]=0.f;
    for (int k0=0; k0<256; k0+=4){
      float4 w4 = *(const float4*)&w[tid*256+k0];
      #pragma unroll
      for (int ti=0; ti<32; ++ti){
        float4 a = *(const float4*)&As[ti*260+k0];
        acc[ti] += a.x*w4.x + a.y*w4.y + a.z*w4.z + a.w*w4.w;
      }
    }
    for (int ti=0; ti<32; ++ti)
      dbl[(size_t)(b*L_ + l0 + ti)*136 + tid] = acc[ti];
  }
}

// ---------------- K5: dt_proj + softplus. dbl[:, :8] -> dt (b,256,L)
__global__ __launch_bounds__(256) void k_dt_proj(const float* __restrict__ dbl,
      const float* __restrict__ w, const float* __restrict__ bias,
      float* __restrict__ dt){
  int id = blockIdx.x*256 + threadIdx.x;
  int l = id & (L_-1);
  int bd = id >> 12;
  int d = bd & 255;
  int b = bd >> 8;
  const float* row = dbl + (size_t)(b*L_ + l)*136;
  float acc = bias[d];
  #pragma unroll
  for (int r=0;r<8;++r) acc += row[r]*w[d*8+r];
  float sp = (acc > 15.f) ? acc : logf(1.f + __expf(acc));
  dt[id] = sp;
}

// ---------------- K6: scan phase 1 — per-chunk local scan: P (decay product), S (end state)
// wave handles 4 chains (b,d0..d0+3,c); lane = di*16+nq, 4 states (n=4nq..4nq+3) per lane
__global__ __launch_bounds__(256) void k_scan1(const float* __restrict__ dt,
      const float* __restrict__ u, const float* __restrict__ dbl,
      const float* __restrict__ A_log,
      float* __restrict__ P, float* __restrict__ S){
  int wg = blockIdx.x*4 + (threadIdx.x >> 6);
  int lane = threadIdx.x & 63;
  int di = lane >> 4, nq = lane & 15;
  int c  = wg & (NC-1);
  int dq = (wg >> 5) & 63;
  int b  = wg >> 11;
  int d  = dq*4 + di;
  int n0 = nq*4;
  float4 al = *(const float4*)&A_log[d*64 + n0];
  float A0=-__expf(al.x), A1=-__expf(al.y), A2=-__expf(al.z), A3=-__expf(al.w);
  float h0=0,h1=0,h2=0,h3=0, p0=1,p1=1,p2=1,p3=1;
  const float* dtp = dt + (b*256+d)*L_ + c*LC;
  const float* up  = u  + (b*256+d)*L_ + c*LC;
  const float* dbase = dbl + (size_t)(b*L_ + c*LC)*136;
  for (int i=0;i<LC;++i){
    float dtv = dtp[i];
    float uv  = up[i];
    float4 Bv = *(const float4*)&dbase[(size_t)i*136 + 8 + n0];
    float du = dtv*uv;
    float e0=__expf(dtv*A0), e1=__expf(dtv*A1), e2=__expf(dtv*A2), e3=__expf(dtv*A3);
    h0 = h0*e0 + du*Bv.x; h1 = h1*e1 + du*Bv.y;
    h2 = h2*e2 + du*Bv.z; h3 = h3*e3 + du*Bv.w;
    p0*=e0; p1*=e1; p2*=e2; p3*=e3;
  }
  size_t idx = ((size_t)((b*256+d)*NC + c))*64 + n0;
  *(float4*)&S[idx] = make_float4(h0,h1,h2,h3);
  *(float4*)&P[idx] = make_float4(p0,p1,p2,p3);
}

// ---------------- K7: scan phase 2 — cross-chunk scan; writes chunk-START state into P
__global__ __launch_bounds__(256) void k_scan2(float* __restrict__ P, const float* __restrict__ S){
  int g = blockIdx.x*256 + threadIdx.x;  // (b*256+d)*64 + n
  int n = g & 63;
  int bd = g >> 6;
  float H = 0.f;
  size_t base = ((size_t)bd*NC)*64 + n;
  for (int c=0;c<NC;++c){
    size_t idx = base + (size_t)c*64;
    float p = P[idx], s = S[idx];
    P[idx] = H;                 // chunk-start state for phase 3
    H = H*p + s;
  }
}

// ---------------- K8: scan phase 3 — replay with correct h0, emit y; fused +u*D, *silu(z)
// y values staged per-wave in LDS, flushed with coalesced float4 stores (fixes 10x write amplification)
__global__ __launch_bounds__(256) void k_scan3(float* __restrict__ dt,
      const float* __restrict__ u, const float* __restrict__ dbl,
      const float* __restrict__ xz, const float* __restrict__ A_log,
      const float* __restrict__ P, const float* __restrict__ Dp){
  __shared__ float Ys[16][132];        // [wave*4+di][i], stride 132 breaks bank alignment
  int wv = threadIdx.x >> 6;
  int wg = blockIdx.x*4 + wv;
  int lane = threadIdx.x & 63;
  int di = lane >> 4, nq = lane & 15;
  int c  = wg & (NC-1);
  int dq = (wg >> 5) & 63;
  int b  = wg >> 11;
  int d  = dq*4 + di;
  int n0 = nq*4;
  float4 al = *(const float4*)&A_log[d*64 + n0];
  float A0=-__expf(al.x), A1=-__expf(al.y), A2=-__expf(al.z), A3=-__expf(al.w);
  size_t sidx = ((size_t)((b*256+d)*NC + c))*64 + n0;
  float4 hv = *(const float4*)&P[sidx];
  float h0=hv.x,h1=hv.y,h2=hv.z,h3=hv.w;
  float Dd = Dp[d];
  float* dtp = dt + (b*256+d)*L_ + c*LC;
  const float* up  = u  + (b*256+d)*L_ + c*LC;
  const float* zp  = xz + (size_t)(b*512 + 256 + d)*L_ + c*LC;
  const float* dbase = dbl + (size_t)(b*L_ + c*LC)*136;
  for (int i=0;i<LC;++i){
    float dtv = dtp[i];
    float uv  = up[i];
    const float* rw = &dbase[(size_t)i*136];
    float4 Bv = *(const float4*)&rw[8 + n0];
    float4 Cv = *(const float4*)&rw[72 + n0];
    float du = dtv*uv;
    float e0=__expf(dtv*A0), e1=__expf(dtv*A1), e2=__expf(dtv*A2), e3=__expf(dtv*A3);
    h0 = h0*e0 + du*Bv.x; h1 = h1*e1 + du*Bv.y;
    h2 = h2*e2 + du*Bv.z; h3 = h3*e3 + du*Bv.w;
    float part = h0*Cv.x + h1*Cv.y + h2*Cv.z + h3*Cv.w;
    part += __shfl_xor(part, 1);
    part += __shfl_xor(part, 2);
    part += __shfl_xor(part, 4);
    part += __shfl_xor(part, 8);   // sum over the 16-lane (64-state) group
    if (nq == 0){
      float zv = zp[i];
      Ys[wv*4+di][i] = (part + uv*Dd) * fsilu(zv);   // stage in LDS
    }
  }
  // coalesced flush: 16 lanes per chain, 2x float4 each -> 512B contiguous per chain
  float4 v0 = *(const float4*)&Ys[wv*4+di][nq*4];
  float4 v1 = *(const float4*)&Ys[wv*4+di][64 + nq*4];
  *(float4*)&dtp[nq*4]      = v0;
  *(float4*)&dtp[64 + nq*4] = v1;
}

// ---------------- K9: out_proj. y=dt (b,256,L) -> t2 token-major (b*L,128)
__global__ __launch_bounds__(256) void k_out_proj(const float* __restrict__ y,
      const float* __restrict__ w, float* __restrict__ t2){
  __shared__ float As[16*260];
  int blk = blockIdx.x;
  int b = blk >> 8;
  int l0 = (blk & 255) << 4;
  int tid = threadIdx.x;
  for (int idx = tid; idx < 16*256; idx += 256){
    int k = idx >> 4, ti = idx & 15;
    As[ti*260 + k] = y[(b*256+k)*L_ + l0 + ti];
  }
  __syncthreads();
  int j = tid & 127;
  int ti0 = (tid >> 7) * 8;
  float acc[8];
  #pragma unroll
  for (int t=0;t<8;++t) acc[t]=0.f;
  for (int k0=0;k0<256;k0+=4){
    float4 w4 = *(const float4*)&w[j*256+k0];
    #pragma unroll
    for (int t=0;t<8;++t){
      float4 a = *(const float4*)&As[(ti0+t)*260+k0];
      acc[t] += a.x*w4.x + a.y*w4.y + a.z*w4.z + a.w*w4.w;
    }
  }
  #pragma unroll
  for (int t=0;t<8;++t)
    t2[(size_t)(b*L_ + l0 + ti0 + t)*128 + j] = acc[t];
}

// ---------------- K10: proj_out + bias + LayerNorm -> t3 channel-major (b,128,L)
__global__ __launch_bounds__(128) void k_proj_out_ln(const float* __restrict__ t2,
      const float* __restrict__ w, const float* __restrict__ bias,
      const float* __restrict__ g, const float* __restrict__ bb,
      float* __restrict__ t3){
  __shared__ float As[16*132];
  __shared__ float Ps[16*8], Qs[16*8];
  __shared__ float Mu[16], Rs[16];
  int blk = blockIdx.x;
  int b = blk >> 8;
  int l0 = (blk & 255) << 4;
  int tid = threadIdx.x;
  for (int idx = tid; idx < 16*128; idx += 128){
    int ti = idx >> 7, k = idx & 127;
    As[ti*132 + k] = t2[(size_t)(b*L_ + l0 + ti)*128 + k];
  }
  __syncthreads();
  int j = tid;
  float acc[16];
  #pragma unroll
  for (int t=0;t<16;++t) acc[t]=bias[j];
  for (int k0=0;k0<128;k0+=4){
    float4 w4 = *(const float4*)&w[j*128+k0];
    #pragma unroll
    for (int t=0;t<16;++t){
      float4 a = *(const float4*)&As[t*132+k0];
      acc[t] += a.x*w4.x + a.y*w4.y + a.z*w4.z + a.w*w4.w;
    }
  }
  __syncthreads();                 // done reading As
  #pragma unroll
  for (int t=0;t<16;++t) As[t*132 + j] = acc[t];
  __syncthreads();
  {
    int ti = tid >> 3, s = tid & 7;
    float sm=0.f, sq=0.f;
    for (int q=0;q<16;++q){
      float v = As[ti*132 + s*16 + q];
      sm += v; sq += v*v;
    }
    Ps[ti*8+s]=sm; Qs[ti*8+s]=sq;
  }
  __syncthreads();
  if (tid < 16){
    float sm=0.f,sq=0.f;
    for (int q=0;q<8;++q){ sm+=Ps[tid*8+q]; sq+=Qs[tid*8+q]; }
    float mu = sm*(1.f/128.f);
    float var = sq*(1.f/128.f) - mu*mu;
    Mu[tid]=mu; Rs[tid]=rsqrtf(var + 1e-5f);
  }
  __syncthreads();
  float gj = g[j], bj = bb[j];
  #pragma unroll
  for (int t=0;t<16;++t){
    float v = (As[t*132+j]-Mu[t])*Rs[t]*gj + bj;
    t3[(size_t)(b*128+j)*L_ + l0 + t] = v;
  }
}

// ---------------- K11: instance norm over L per (b,c) + leaky relu -> f (b,128,L)
__global__ __launch_bounds__(256) void k_inorm(const float* __restrict__ t3,
      const float* __restrict__ g, const float* __restrict__ bb,
      float* __restrict__ f){
  __shared__ float Sm[4], Sq[4];
  __shared__ float MuS, RsS;
  int bc = blockIdx.x;
  int c = bc & 127;
  const float* src = t3 + (size_t)bc*L_;
  int tid = threadIdx.x;
  float sm=0.f, sq=0.f;
  for (int i=tid;i<L_;i+=256){ float v=src[i]; sm+=v; sq+=v*v; }
  #pragma unroll
  for (int off=32;off;off>>=1){ sm += __shfl_xor(sm,off); sq += __shfl_xor(sq,off); }
  if ((tid & 63)==0){ Sm[tid>>6]=sm; Sq[tid>>6]=sq; }
  __syncthreads();
  if (tid==0){
    float a=Sm[0]+Sm[1]+Sm[2]+Sm[3], q=Sq[0]+Sq[1]+Sq[2]+Sq[3];
    float mu=a*(1.f/L_), var=q*(1.f/L_)-mu*mu;
    MuS=mu; RsS=rsqrtf(var+1e-5f);
  }
  __syncthreads();
  float mu=MuS, rs=RsS, gc=g[c], b2=bb[c];
  float* dst = f + (size_t)bc*L_;
  for (int i=tid;i<L_;i+=256){
    float v=(src[i]-mu)*rs*gc + b2;
    dst[i] = (v>=0.f)? v : 0.01f*v;
  }
}

// ---------------- K12: 3x3 SAME conv, 128->128. f (b,128,64,64) -> out
__global__ __launch_bounds__(256) void k_conv2d(const float* __restrict__ f,
      const float* __restrict__ w, const float* __restrict__ bias,
      float* __restrict__ out){
  __shared__ float Fs[18*20];
  int blk = blockIdx.x;
  int tile = blk & 15;
  int cog = (blk >> 4) & 15;
  int b = blk >> 8;
  int h0 = (tile >> 2) * 16, w0 = (tile & 3) * 16;
  int co0 = cog*8;
  int tid = threadIdx.x;
  int tx = tid & 15, ty = tid >> 4;
  float acc[8];
  #pragma unroll
  for (int i=0;i<8;++i) acc[i]=0.f;
  for (int ci=0; ci<128; ++ci){
    __syncthreads();
    for (int idx=tid; idx<18*18; idx+=256){
      int r = idx/18, cc = idx%18;
      int h = h0-1+r, ww = w0-1+cc;
      float v = 0.f;
      if (h>=0 && h<64 && ww>=0 && ww<64)
        v = f[((size_t)(b*128+ci))*4096 + h*64 + ww];
      Fs[r*20+cc] = v;
    }
    __syncthreads();
    const float* wp = w + ((size_t)co0*128 + ci)*9;    // wave-uniform -> s_load
    #pragma unroll
    for (int ky=0;ky<3;++ky)
    #pragma unroll
    for (int kx=0;kx<3;++kx){
      float lv = Fs[(ty+ky)*20 + tx+kx];
      #pragma unroll
      for (int co=0;co<8;++co)
        acc[co] += lv * wp[(size_t)co*128*9 + ky*3+kx];
    }
  }
  #pragma unroll
  for (int co=0;co<8;++co)
    out[((size_t)(b*128+co0+co))*4096 + (h0+ty)*64 + (w0+tx)] = acc[co] + bias[co0+co];
}

extern "C" void kernel_launch(void* const* d_in, const int* in_sizes, int n_in,
                              void* d_out, int out_size, void* d_ws, size_t ws_size,
                              hipStream_t stream){
  const float* x     = (const float*)d_in[0];
  const float* piw   = (const float*)d_in[1];
  const float* pib   = (const float*)d_in[2];
  const float* ipw   = (const float*)d_in[3];
  const float* c1w   = (const float*)d_in[4];
  const float* c1b   = (const float*)d_in[5];
  const float* xpw   = (const float*)d_in[6];
  const float* dtw   = (const float*)d_in[7];
  const float* dtb   = (const float*)d_in[8];
  const float* alog  = (const float*)d_in[9];
  const float* Dp    = (const float*)d_in[10];
  const float* opw   = (const float*)d_in[11];
  const float* pow_  = (const float*)d_in[12];
  const float* pob   = (const float*)d_in[13];
  const float* lng   = (const float*)d_in[14];
  const float* lnb   = (const float*)d_in[15];
  const float* ing   = (const float*)d_in[16];
  const float* inb   = (const float*)d_in[17];
  const float* c2w   = (const float*)d_in[18];
  const float* c2b   = (const float*)d_in[19];
  float* out = (float*)d_out;

  // workspace layout (floats); total 46,399,488 floats = 185.6 MB
  float* ws  = (float*)d_ws;
  float* t1  = ws;                    // 4,194,304   (b,128,L); reused as t2 (token-major) after scan
  float* xz  = t1 + 4194304;          // 16,777,216  (b,512,L)
  float* u   = xz + 16777216;         // 8,388,608   (b,256,L); reused as f after instnorm
  float* dbl = u  + 8388608;          // 4,456,448   (b*L,136); reused as t3 (b,128,L) after scan
  float* dt  = dbl + 4456448;         // 8,388,608   (b,256,L); y written in place by scan3
  float* S   = dt + 8388608;          // 4,194,304
  float* P   = t1;                    // alias t1 (free between in_proj and out_proj)
  float* t2  = t1;
  float* t3  = dbl;
  float* fbuf= u;

  k_proj_in   <<<dim3(512),   dim3(256), 0, stream>>>(x, piw, pib, t1);
  k_in_proj   <<<dim3(2048),  dim3(256), 0, stream>>>(t1, ipw, xz);
  k_conv1d    <<<dim3(32768), dim3(256), 0, stream>>>(xz, c1w, c1b, u);
  k_x_proj    <<<dim3(1024),  dim3(256), 0, stream>>>(u, xpw, dbl);
  k_dt_proj   <<<dim3(32768), dim3(256), 0, stream>>>(dbl, dtw, dtb, dt);
  k_scan1     <<<dim3(4096),  dim3(256), 0, stream>>>(dt, u, dbl, alog, P, S);
  k_scan2     <<<dim3(512),   dim3(256), 0, stream>>>(P, S);
  k_scan3     <<<dim3(4096),  dim3(256), 0, stream>>>(dt, u, dbl, xz, alog, P, Dp);
  k_out_proj  <<<dim3(2048),  dim3(256), 0, stream>>>(dt, opw, t2);
  k_proj_out_ln<<<dim3(2048), dim3(128), 0, stream>>>(t2, pow_, pob, lng, lnb, t3);
  k_inorm     <<<dim3(1024),  dim3(256), 0, stream>>>(t3, ing, inb, fbuf);
  k_conv2d    <<<dim3(2048),  dim3(256), 0, stream>>>(fbuf, c2w, c2b, out);
}